// Round 7
// baseline (1207.523 us; speedup 1.0000x reference)
//
#include <hip/hip_runtime.h>
#include <math.h>

#define P_TOT 4096
#define IN_DIM 1024
#define DDIM 24
#define MKEYS 4096
#define HDIM 256
#define CCENT 256
#define KTOP 32

typedef short bf16x8 __attribute__((ext_vector_type(8)));
typedef float f32x4 __attribute__((ext_vector_type(4)));

// ---- workspace layout (float units) ----
static const size_t o_Yq      = 0;                                   // 2x 4096x72 f32 (split-K halves)
static const size_t o_Yp      = o_Yq + (size_t)2*P_TOT*72;           // 4096x256 f32
static const size_t o_q       = o_Yp + (size_t)P_TOT*256;            // 4096x24 f32
static const size_t o_qq      = o_q + (size_t)P_TOT*DDIM;            // 4096 f32
static const size_t o_KF      = o_qq + P_TOT;                        // 4096x512 f32
static const size_t o_keynorm = o_KF + (size_t)P_TOT*512;            // 4096
static const size_t o_centnorm= o_keynorm + MKEYS;                   // 256
static const size_t o_coef    = o_centnorm + CCENT;                  // 64
static const size_t o_vread   = o_coef + 64;                         // 4096x72 f32
static const size_t o_keysT   = o_vread + (size_t)P_TOT*72;          // 24x4096 f32
static const size_t o_sel     = o_keysT + (size_t)DDIM*MKEYS;        // 256 int
static const size_t o_mask    = o_sel + 256;                         // 4096 int
static const size_t o_count   = o_mask + MKEYS;                      // 64 int
static const size_t o_A6      = o_count + 64;                        // 4096x3072 bf16 [x0|x1|x2]
static const size_t o_W6T     = o_A6 + (size_t)P_TOT*3072/2;         // 72x6144 bf16
static const size_t o_W2cat   = o_W6T + (size_t)72*6144/2;           // 256x2048 bf16 [wh|wh]
static const size_t o_KCbf    = o_W2cat + (size_t)256*2048/2;        // 4096x512 bf16
static const size_t o_TTT     = o_KCbf + (size_t)P_TOT*512/2;        // 512x512 bf16
static const size_t o_Xcatbf  = o_TTT + (size_t)512*512/2;           // 4096x512 bf16
static const size_t o_W2T     = o_Xcatbf + (size_t)P_TOT*512/2;      // 72x512 bf16
static const size_t o_membf   = o_W2T + (size_t)72*512/2;            // 4096x96 bf16
static const size_t o_WoutT   = o_membf + (size_t)P_TOT*96/2;        // 1024x96 bf16

__device__ __forceinline__ float gelu_f(float x){
    return 0.5f * x * (1.0f + erff(x * 0.70710678118654752f));
}
__device__ __forceinline__ ushort f2bf(float f){
    union { float f; unsigned u; } a; a.f = f;
    unsigned u = a.u;
    return (ushort)((u + 0x7fffu + ((u >> 16) & 1u)) >> 16);
}
__device__ __forceinline__ float bf2f(ushort b){
    union { unsigned u; float f; } a; a.u = ((unsigned)b) << 16;
    return a.f;
}

#define TWO_PI_F 6.2831853071795864769f
#define STEP_F   0.024543692606170262f   // 2*pi/256

// ---------------- setup kernels ----------------
__global__ void setup_small(const float* __restrict__ fw, const float* __restrict__ cent,
                            float* __restrict__ coefp, float* __restrict__ centnorm,
                            int* __restrict__ sel, int* __restrict__ count)
{
    int t = threadIdx.x;
    if (t == 0){
        float m = fmaxf(fmaxf(fw[0],fw[1]),fmaxf(fw[2],fw[3]));
        float e0=expf(fw[0]-m), e1=expf(fw[1]-m), e2=expf(fw[2]-m), e3=expf(fw[3]-m);
        float s = e0+e1+e2+e3;
        *coefp = (e0 + e1*0.25f + e2*0.0625f + e3*0.015625f) / s;
        *count = 0;
    }
    if (t < CCENT){
        sel[t] = 0;
        float s = 0.f;
        #pragma unroll
        for (int d=0; d<DDIM; ++d){ float v = cent[t*DDIM+d]; s += v*v; }
        centnorm[t] = s;
    }
}

__global__ void key_setup(const float* __restrict__ keys, float* __restrict__ keynorm,
                          float* __restrict__ keysT)
{
    int m = blockIdx.x*256 + threadIdx.x;
    float s = 0.f;
    #pragma unroll
    for (int d=0; d<DDIM; ++d){
        float v = keys[m*DDIM+d]; s += v*v;
        keysT[(size_t)d*MKEYS + m] = v;
    }
    keynorm[m] = s;
}

// x -> triple-split bf16: A6[p] = [x0(1024) | x1(1024) | x2(1024)]
__global__ void conv_x3(const float* __restrict__ x, ushort* __restrict__ A6)
{
    int i = blockIdx.x*256 + threadIdx.x;
    int p = i >> 8, j = (i & 255) * 4;
    float4 v = *(const float4*)&x[(size_t)p*IN_DIM + j];
    ushort4 s0, s1, s2;
    float r;
    s0.x=f2bf(v.x); r=v.x-bf2f(s0.x); s1.x=f2bf(r); s2.x=f2bf(r-bf2f(s1.x));
    s0.y=f2bf(v.y); r=v.y-bf2f(s0.y); s1.y=f2bf(r); s2.y=f2bf(r-bf2f(s1.y));
    s0.z=f2bf(v.z); r=v.z-bf2f(s0.z); s1.z=f2bf(r); s2.z=f2bf(r-bf2f(s1.z));
    s0.w=f2bf(v.w); r=v.w-bf2f(s0.w); s1.w=f2bf(r); s2.w=f2bf(r-bf2f(s1.w));
    *(ushort4*)&A6[(size_t)p*3072 + j]        = s0;
    *(ushort4*)&A6[(size_t)p*3072 + 1024 + j] = s1;
    *(ushort4*)&A6[(size_t)p*3072 + 2048 + j] = s2;
}

// W6T[n][seg*1024+k] : B-side segment pattern [w0,w1,w0,w2,w1,w0]
__global__ void conv_W6(const float* __restrict__ Win, ushort* __restrict__ W6T)
{
    int idx = blockIdx.x*256 + threadIdx.x;    // 72*6144
    if (idx >= 72*6144) return;
    int n = idx / 6144, kp = idx - n*6144;
    int seg = kp >> 10, kk = kp & 1023;
    int sb = (0x012010 >> (seg << 2)) & 0xF;
    float w = Win[kk*72 + n];
    ushort w0 = f2bf(w);
    float r1 = w - bf2f(w0);
    ushort w1 = f2bf(r1);
    ushort w2 = f2bf(r1 - bf2f(w1));
    W6T[idx] = (sb == 0) ? w0 : (sb == 1 ? w1 : w2);
}

// W2cat[n] = [wh(1024) | wh(1024)], n = phase col (Wk col)
__global__ void conv_W2cat(const float* __restrict__ Wk, ushort* __restrict__ W2cat)
{
    int idx = blockIdx.x*256 + threadIdx.x;    // 256*2048
    int n = idx >> 11, k = idx & 2047;
    int kk = k & 1023;
    W2cat[idx] = f2bf(Wk[kk*256 + n]);
}

__global__ void conv_WoutT(const float* __restrict__ Wout, ushort* __restrict__ WoutT)
{
    int idx = blockIdx.x*256 + threadIdx.x;    // 1024*96
    int n = idx / 96, k = idx - n*96;
    float v = (k < 72) ? Wout[(size_t)k*IN_DIM + n] : 0.f;
    WoutT[idx] = f2bf(v);
}

// forward-DFT + entangle folded, transposed bf16: TTT[c][r]
__global__ void build_TTT(const float* __restrict__ ek, ushort* __restrict__ TTT)
{
    int idx = blockIdx.x*256 + threadIdx.x;   // 512*512, idx = c*512 + r
    int c = idx >> 9, r = idx & 511;
    int n = c & 255, h = r & 255;
    float th = (float)((n*h) & 255) * STEP_F - ek[n];
    float sn, cs; sincosf(th, &sn, &cs);
    float v;
    if (r < 256) v = (c < 256) ? cs : -sn;
    else         v = (c < 256) ? sn : cs;
    TTT[idx] = f2bf(v);
}

// inverse-DFT folded into W_read, transposed bf16: W2T[j][k]
__global__ void build_W2T(const float* __restrict__ Wr, ushort* __restrict__ W2T)
{
    __shared__ float tab[256];
    int t = threadIdx.x;
    tab[t] = cosf((float)t * STEP_F);
    __syncthreads();
    int idx = blockIdx.x*256 + t;   // 72*512
    if (idx >= 72*512) return;
    int j = idx >> 9, k = idx & 511;
    int n = k & 255;
    float acc = 0.f;
    for (int h=0; h<256; ++h){
        int xdx = (n*h) & 255;
        float c = tab[xdx], s = tab[(xdx+192) & 255];
        float w1 = Wr[h*72 + j], w2 = Wr[(256+h)*72 + j];
        acc += (k < 256) ? (c*w1 + s*w2) : (c*w2 - s*w1);
    }
    W2T[idx] = f2bf(acc * (1.f/256.f));
}

// ---------------- bf16 MFMA GEMM (with optional split-K over blockIdx.z) ----------------
// amode==0: A k-index = kk & aMask.  amode==1: 6-term split pattern [x0,x0,x1,x0,x1,x2].
__global__ __launch_bounds__(256) void gemm_bf16(
    const ushort* __restrict__ A, const ushort* __restrict__ BT,
    float* __restrict__ C, const float* __restrict__ bias,
    const float* __restrict__ addm, ushort* __restrict__ Cbf,
    int M, int N, int Kloop, int Nb, int NbfPad, int lda, int ldb, int aMask,
    int amode, int kChunk, size_t zStride)
{
    __shared__ __align__(16) ushort As[64][40];
    __shared__ __align__(16) ushort Bs[64][40];
    const int tid = threadIdx.x;
    const int lane = tid & 63, wid = tid >> 6;
    const int wm = wid >> 1, wn = wid & 1;
    const int m0 = blockIdx.y * 64, n0 = blockIdx.x * 64;
    const int fr = lane & 15, fc = lane >> 4;
    const int srow = tid >> 2, schunk = (tid & 3) * 8;
    const int kStart = blockIdx.z * kChunk;
    const int kEnd = (kStart + kChunk < Kloop) ? (kStart + kChunk) : Kloop;
    if (blockIdx.z){ C += zStride; bias = nullptr; addm = nullptr; Cbf = nullptr; }
    f32x4 acc[2][2] = {};
    for (int k0 = kStart; k0 < kEnd; k0 += 32){
        int kk = k0 + schunk;
        int ka;
        if (amode) ka = (((0x210100 >> ((kk >> 10) << 2)) & 0xF) << 10) | (kk & 1023);
        else       ka = kk & aMask;
        *(bf16x8*)&As[srow][schunk] =
            *(const bf16x8*)&A[(size_t)(m0 + srow) * lda + ka];
        {
            int n = n0 + srow;
            bf16x8 v = {};
            if (n < Nb) v = *(const bf16x8*)&BT[(size_t)n * ldb + kk];
            *(bf16x8*)&Bs[srow][schunk] = v;
        }
        __syncthreads();
        bf16x8 a0 = *(bf16x8*)&As[wm*32 + fr][fc*8];
        bf16x8 a1 = *(bf16x8*)&As[wm*32 + 16 + fr][fc*8];
        bf16x8 b0 = *(bf16x8*)&Bs[wn*32 + fr][fc*8];
        bf16x8 b1 = *(bf16x8*)&Bs[wn*32 + 16 + fr][fc*8];
        acc[0][0] = __builtin_amdgcn_mfma_f32_16x16x32_bf16(a0, b0, acc[0][0], 0,0,0);
        acc[0][1] = __builtin_amdgcn_mfma_f32_16x16x32_bf16(a0, b1, acc[0][1], 0,0,0);
        acc[1][0] = __builtin_amdgcn_mfma_f32_16x16x32_bf16(a1, b0, acc[1][0], 0,0,0);
        acc[1][1] = __builtin_amdgcn_mfma_f32_16x16x32_bf16(a1, b1, acc[1][1], 0,0,0);
        __syncthreads();
    }
    #pragma unroll
    for (int mi=0; mi<2; ++mi){
        #pragma unroll
        for (int ni=0; ni<2; ++ni){
            #pragma unroll
            for (int rr=0; rr<4; ++rr){
                int gm = m0 + wm*32 + mi*16 + fc*4 + rr;
                int gn = n0 + wn*32 + ni*16 + fr;
                float v = acc[mi][ni][rr];
                if (gn < N){
                    if (bias) v += bias[gn];
                    if (addm) v += addm[(size_t)gm*N + gn];
                    if (C) C[(size_t)gm*N + gn] = v;
                } else v = 0.f;
                if (Cbf && gn < NbfPad)
                    Cbf[(size_t)gm*NbfPad + gn] = f2bf(v);
            }
        }
    }
}

// ---------------- LN+GELU+ricci (Yq = half0 + half1) + phase (from Yp) ----------------
__global__ __launch_bounds__(256) void post_proj(
    const float* __restrict__ Yq, const float* __restrict__ Yp,
    const float* __restrict__ ricci,
    float* __restrict__ q, float* __restrict__ qq, ushort* __restrict__ KCbf)
{
    int wave = threadIdx.x >> 6, lane = threadIdx.x & 63;
    int p = blockIdx.x*4 + wave;
    __shared__ float zsh[4][72];
    __shared__ float zbsh[4][24];
    const float* Yr  = Yq + (size_t)p*72;
    const float* Yr2 = Yq + (size_t)P_TOT*72 + (size_t)p*72;
    float v1 = Yr[lane] + Yr2[lane];
    float v2 = (lane < 8) ? (Yr[64+lane] + Yr2[64+lane]) : 0.f;
    float s = v1 + v2, s2 = v1*v1 + v2*v2;
    #pragma unroll
    for (int off=32; off; off>>=1){ s += __shfl_xor(s,off); s2 += __shfl_xor(s2,off); }
    float mean = s * (1.f/72.f);
    float var  = s2 * (1.f/72.f) - mean*mean;
    float rstd = rsqrtf(var + 1e-5f);
    zsh[wave][lane] = gelu_f((v1-mean)*rstd);
    if (lane < 8) zsh[wave][64+lane] = gelu_f((v2-mean)*rstd);
    __syncthreads();
    if (lane < 24){
        float zb = (zsh[wave][lane*3] + zsh[wave][lane*3+1] + zsh[wave][lane*3+2]) * (1.f/3.f);
        zbsh[wave][lane] = zb;
    }
    __syncthreads();
    float qd = 0.f;
    if (lane < 24){
        #pragma unroll
        for (int e=0;e<24;++e) qd += zbsh[wave][e] * ricci[e*24+lane];
        q[(size_t)p*DDIM + lane] = qd;
    }
    float qs = (lane<24) ? qd*qd : 0.f;
    #pragma unroll
    for (int off=32; off; off>>=1) qs += __shfl_xor(qs,off);
    if (lane == 0) qq[p] = qs;
    const float* Ypr = Yp + (size_t)p*256;
    #pragma unroll
    for (int j=0;j<4;++j){
        int h = lane + 64*j;
        float u = Ypr[h];
        float ph = TWO_PI_F / (1.f + expf(-u));
        float sn, cs; sincosf(ph, &sn, &cs);
        KCbf[(size_t)p*512 + h]       = f2bf(cs);
        KCbf[(size_t)p*512 + 256 + h] = f2bf(sn);
    }
}

// ---------------- centroid top-8 (fp32), global union ----------------
__global__ __launch_bounds__(256) void cent_topk(
    const float* __restrict__ q, const float* __restrict__ qq,
    const float* __restrict__ centroids, const float* __restrict__ centnorm,
    int* __restrict__ sel)
{
    int wave = threadIdx.x >> 6, lane = threadIdx.x & 63;
    int p = blockIdx.x*4 + wave;
    __shared__ float qsh[4][24];
    if (lane < 24) qsh[wave][lane] = q[(size_t)p*DDIM + lane];
    __syncthreads();
    float qv = qq[p];
    float d[4]; int ci[4];
    #pragma unroll
    for (int j=0;j<4;++j){
        int c = lane + 64*j;
        float dot = 0.f;
        #pragma unroll
        for (int e=0;e<24;++e) dot += qsh[wave][e]*centroids[c*24+e];
        d[j] = qv + centnorm[c] - 2.f*dot;
        ci[j] = c;
    }
    for (int k=0;k<8;++k){
        float mv = d[0]; int mi = ci[0];
        #pragma unroll
        for (int j=1;j<4;++j) if (d[j] < mv || (d[j]==mv && ci[j]<mi)){ mv=d[j]; mi=ci[j]; }
        #pragma unroll
        for (int off=32; off; off>>=1){
            float ov = __shfl_xor(mv,off); int oi = __shfl_xor(mi,off);
            if (ov < mv || (ov==mv && oi<mi)){ mv=ov; mi=oi; }
        }
        if ((mi & 63) == lane){
            int j = mi >> 6;
            if (j==0) d[0]=INFINITY; else if (j==1) d[1]=INFINITY;
            else if (j==2) d[2]=INFINITY; else d[3]=INFINITY;
            sel[mi] = 1;
        }
    }
}

__global__ void mask_count(const int* __restrict__ sel, const int* __restrict__ cids,
                           int* __restrict__ maskKey, int* __restrict__ count)
{
    int m = blockIdx.x*256 + threadIdx.x;
    int v = sel[cids[m]];
    maskKey[m] = v;
    int lane = threadIdx.x & 63;
    #pragma unroll
    for (int off=32; off; off>>=1) v += __shfl_xor(v, off);
    if (lane == 0) atomicAdd(count, v);
}

// ---------------- top-32 select: per-wave sorted-list extraction, barrier-free loop ----------------
__global__ __launch_bounds__(256) void select_read(
    const float* __restrict__ keysT,
    const float* __restrict__ q, const float* __restrict__ qq,
    const float* __restrict__ keynorm, const int* __restrict__ maskKey,
    const int* __restrict__ count, const float* __restrict__ coefp,
    const float* __restrict__ values, const float* __restrict__ hr,
    const float* __restrict__ hi, const float* __restrict__ KF,
    float* __restrict__ vread, ushort* __restrict__ Xcatbf)
{
    const int p = blockIdx.x;
    const int t = threadIdx.x;
    const int w = t >> 6, lane = t & 63;
    __shared__ float qsh[24];
    __shared__ float candV[4][32];
    __shared__ int   candI[4][32];
    __shared__ float sv[KTOP]; __shared__ int sidx[KTOP];
    __shared__ float sw[KTOP];
    __shared__ float ssum_sh;

    bool useAll = (*count) < 32;
    float qv = qq[p];
    if (t < 24) qsh[t] = q[(size_t)p*DDIM + t];
    __syncthreads();

    // distances: wave w owns keys [1024w, 1024w+1024), key m = 1024w + lane + 64*i
    float acc[16];
    #pragma unroll
    for (int i=0;i<16;++i) acc[i] = 0.f;
    {
        const float* kb = keysT + 1024*w + lane;
        for (int e=0;e<24;++e){
            float qd = qsh[e];
            const float* kr = kb + (size_t)e*MKEYS;
            #pragma unroll
            for (int i=0;i<16;++i) acc[i] += qd * kr[64*i];
        }
    }
    const int mbase = 1024*w + lane;
    float dv[16]; int di[16];
    #pragma unroll
    for (int i=0;i<16;++i){
        int m = mbase + 64*i;
        float dd = qv + keynorm[m] - 2.f*acc[i];
        bool ok = useAll || (maskKey[m] != 0);
        dv[i] = ok ? dd : INFINITY;
        di[i] = m;
    }

    // in-register bitonic sort of 16 (v,idx) pairs, ascending (static indices)
    #pragma unroll
    for (int k=2; k<=16; k<<=1){
        #pragma unroll
        for (int j=k>>1; j>0; j>>=1){
            #pragma unroll
            for (int i=0;i<16;++i){
                int l = i ^ j;
                if (l > i){
                    bool up = ((i & k) == 0);
                    bool bad = up ? (dv[i] > dv[l] || (dv[i]==dv[l] && di[i]>di[l]))
                                  : (dv[i] < dv[l] || (dv[i]==dv[l] && di[i]<di[l]));
                    if (bad){
                        float tv=dv[i]; dv[i]=dv[l]; dv[l]=tv;
                        int   ti=di[i]; di[i]=di[l]; di[l]=ti;
                    }
                }
            }
        }
    }

    // per-wave top-32 extraction (no barriers): head = dv[0]
    #pragma unroll 1
    for (int k=0;k<KTOP;++k){
        float v = dv[0]; int ix = di[0];
        #pragma unroll
        for (int off=32; off; off>>=1){
            float ov = __shfl_xor(v,off); int oi = __shfl_xor(ix,off);
            if (ov < v || (ov==v && oi<ix)){ v=ov; ix=oi; }
        }
        if (lane==0){ candV[w][k]=v; candI[w][k]=ix; }
        if (ix == di[0]){  // owner: shift sorted list (static moves)
            #pragma unroll
            for (int j=0;j<15;++j){ dv[j]=dv[j+1]; di[j]=di[j+1]; }
            dv[15]=INFINITY; di[15]=0x7fffffff;
        }
    }
    __syncthreads();

    // merge 128 candidates -> global sorted top-32 (wave 0)
    if (w == 0){
        const float* cvf = &candV[0][0];
        const int*   cif = &candI[0][0];
        float e0 = cvf[lane];    int i0 = cif[lane];
        float e1 = cvf[lane+64]; int i1 = cif[lane+64];
        #pragma unroll 1
        for (int k=0;k<KTOP;++k){
            bool first = (e0 < e1) || (e0==e1 && i0<i1);
            float v = first ? e0 : e1;
            int  ix = first ? i0 : i1;
            #pragma unroll
            for (int off=32; off; off>>=1){
                float ov = __shfl_xor(v,off); int oi = __shfl_xor(ix,off);
                if (ov < v || (ov==v && oi<ix)){ v=ov; ix=oi; }
            }
            if (lane==0){ sv[k]=v; sidx[k]=ix; }
            if (ix == i0){ e0 = INFINITY; i0 = 0x7fffffff; }
            else if (ix == i1){ e1 = INFINITY; i1 = 0x7fffffff; }
        }
    }
    __syncthreads();

    float coef = *coefp;
    if (t < KTOP) sw[t] = expf(-coef * (sv[t] - sv[0]));
    __syncthreads();
    if (t == 0){
        float s = 0.f;
        #pragma unroll
        for (int k=0;k<KTOP;++k) s += sw[k];
        ssum_sh = 1.f / s;
    }
    __syncthreads();
    float inv = ssum_sh;

    if (t < 72){
        float a = 0.f;
        for (int k=0;k<KTOP;++k) a += sw[k]*values[(size_t)sidx[k]*72 + t];
        vread[(size_t)p*72 + t] = a * inv;
    }
    {
        int h = t;
        float sr = 0.f, si = 0.f;
        for (int k=0;k<KTOP;++k){
            float wv = sw[k];
            size_t off = (size_t)sidx[k]*HDIM + h;
            sr += wv*hr[off]; si += wv*hi[off];
        }
        sr *= inv; si *= inv;
        float Rk = KF[(size_t)p*512 + h], Ik = KF[(size_t)p*512 + 256 + h];
        Xcatbf[(size_t)p*512 + h]       = f2bf(sr*Rk + si*Ik);
        Xcatbf[(size_t)p*512 + 256 + h] = f2bf(si*Rk - sr*Ik);
    }
}

// ---------------- final LN+GELU, in place on d_out ----------------
__global__ __launch_bounds__(256) void ln_gelu_out(float* __restrict__ O)
{
    int p = blockIdx.x; int t = threadIdx.x;
    float4 v = *(float4*)&O[(size_t)p*IN_DIM + t*4];
    float s  = v.x+v.y+v.z+v.w;
    float s2 = v.x*v.x+v.y*v.y+v.z*v.z+v.w*v.w;
    #pragma unroll
    for (int off=32; off; off>>=1){ s += __shfl_xor(s,off); s2 += __shfl_xor(s2,off); }
    __shared__ float as[4], as2[4];
    int lane = t & 63, w = t >> 6;
    if (lane == 0){ as[w] = s; as2[w] = s2; }
    __syncthreads();
    s = as[0]+as[1]+as[2]+as[3];
    s2 = as2[0]+as2[1]+as2[2]+as2[3];
    float mean = s * (1.f/1024.f);
    float var  = s2 * (1.f/1024.f) - mean*mean;
    float rstd = rsqrtf(var + 1e-5f);
    v.x = gelu_f((v.x-mean)*rstd);
    v.y = gelu_f((v.y-mean)*rstd);
    v.z = gelu_f((v.z-mean)*rstd);
    v.w = gelu_f((v.w-mean)*rstd);
    *(float4*)&O[(size_t)p*IN_DIM + t*4] = v;
}

extern "C" void kernel_launch(void* const* d_in, const int* in_sizes, int n_in,
                              void* d_out, int out_size, void* d_ws, size_t ws_size,
                              hipStream_t stream)
{
    const float* x      = (const float*)d_in[0];
    const float* keys   = (const float*)d_in[1];
    const float* values = (const float*)d_in[2];
    const float* W_in   = (const float*)d_in[3];
    const float* b_in   = (const float*)d_in[4];
    const float* ricci  = (const float*)d_in[5];
    const float* fw     = (const float*)d_in[6];
    const float* cent   = (const float*)d_in[7];
    const float* Wk     = (const float*)d_in[8];
    const float* bk     = (const float*)d_in[9];
    const float* ek     = (const float*)d_in[10];
    const float* hr     = (const float*)d_in[11];
    const float* hi     = (const float*)d_in[12];
    const float* Wr     = (const float*)d_in[13];
    const float* brd    = (const float*)d_in[14];
    const float* W_out  = (const float*)d_in[15];
    const float* b_out  = (const float*)d_in[16];
    const int*   cids   = (const int*)d_in[17];
    float* ws  = (float*)d_ws;
    float* out = (float*)d_out;
    int* sel   = (int*)(ws + o_sel);
    int* mask  = (int*)(ws + o_mask);
    int* count = (int*)(ws + o_count);
    ushort* A6     = (ushort*)(ws + o_A6);
    ushort* W6T    = (ushort*)(ws + o_W6T);
    ushort* W2cat  = (ushort*)(ws + o_W2cat);
    ushort* KCbf   = (ushort*)(ws + o_KCbf);
    ushort* TTT    = (ushort*)(ws + o_TTT);
    ushort* Xcatbf = (ushort*)(ws + o_Xcatbf);
    ushort* W2T    = (ushort*)(ws + o_W2T);
    ushort* membf  = (ushort*)(ws + o_membf);
    ushort* WoutT  = (ushort*)(ws + o_WoutT);
    const int NOMASK = 0x7fffffff;

    setup_small<<<1,256,0,stream>>>(fw, cent, ws+o_coef, ws+o_centnorm, sel, count);
    key_setup<<<16,256,0,stream>>>(keys, ws+o_keynorm, ws+o_keysT);
    conv_x3<<<4096,256,0,stream>>>(x, A6);
    conv_W6<<<(72*6144+255)/256,256,0,stream>>>(W_in, W6T);
    conv_W2cat<<<2048,256,0,stream>>>(Wk, W2cat);
    conv_WoutT<<<(IN_DIM*96)/256,256,0,stream>>>(W_out, WoutT);
    build_TTT<<<1024,256,0,stream>>>(ek, TTT);
    build_W2T<<<144,256,0,stream>>>(Wr, W2T);

    // Yq = x @ W_in + b_in : 6-term bf16 split MFMA, split-K z=2 (segs 0-2 | 3-5)
    gemm_bf16<<<dim3(2,64,2),256,0,stream>>>(A6, W6T, ws+o_Yq, b_in, nullptr, nullptr,
                                             P_TOT, 72, 6144, 72, 0, 3072, 6144, NOMASK, 1,
                                             3072, (size_t)P_TOT*72);
    // Yp = x @ Wk + bk (smooth phase path): [x0|x1] @ [wh|wh]
    gemm_bf16<<<dim3(4,64,1),256,0,stream>>>(A6, W2cat, ws+o_Yp, bk, nullptr, nullptr,
                                             P_TOT, 256, 2048, 256, 0, 3072, 2048, NOMASK, 0,
                                             2048, 0);
    post_proj<<<1024,256,0,stream>>>(ws+o_Yq, ws+o_Yp, ricci, ws+o_q, ws+o_qq, KCbf);
    // KF = KC @ TT  (forward FFT + entangle, smooth)
    gemm_bf16<<<dim3(8,64,1),256,0,stream>>>(KCbf, TTT, ws+o_KF, nullptr, nullptr, nullptr,
                                             P_TOT, 512, 512, 512, 0, 512, 512, NOMASK, 0,
                                             512, 0);
    cent_topk<<<1024,256,0,stream>>>(ws+o_q, ws+o_qq, cent, ws+o_centnorm, sel);
    mask_count<<<16,256,0,stream>>>(sel, cids, mask, count);
    select_read<<<P_TOT,256,0,stream>>>(ws+o_keysT, ws+o_q, ws+o_qq, ws+o_keynorm,
                                        mask, count, ws+o_coef, values, hr, hi, ws+o_KF,
                                        ws+o_vread, Xcatbf);
    // mem = Xcat @ W2 + b_read + vread  -> bf16 (padded to 96 cols)
    gemm_bf16<<<dim3(2,64,1),256,0,stream>>>(Xcatbf, W2T, nullptr, brd, ws+o_vread, membf,
                                             P_TOT, 72, 512, 72, 96, 512, 512, NOMASK, 0,
                                             512, 0);
    // out = mem @ W_out + b_out
    gemm_bf16<<<dim3(16,64,1),256,0,stream>>>(membf, WoutT, out, b_out, nullptr, nullptr,
                                              P_TOT, IN_DIM, 96, IN_DIM, 0, 96, 96, NOMASK, 0,
                                              96, 0);
    ln_gelu_out<<<P_TOT,256,0,stream>>>(out);
}

// Round 8
// 314.490 us; speedup vs baseline: 3.8396x; 3.8396x over previous
//
#include <hip/hip_runtime.h>
#include <math.h>

#define P_TOT 4096
#define IN_DIM 1024
#define DDIM 24
#define MKEYS 4096
#define HDIM 256
#define CCENT 256
#define KTOP 32

typedef short bf16x8 __attribute__((ext_vector_type(8)));
typedef float f32x4 __attribute__((ext_vector_type(4)));

// ---- workspace layout (float units) ----
static const size_t o_Yq      = 0;                                   // 2x 4096x72 f32 (split-K halves)
static const size_t o_Yp      = o_Yq + (size_t)2*P_TOT*72;           // 4096x256 f32
static const size_t o_q       = o_Yp + (size_t)P_TOT*256;            // 4096x24 f32
static const size_t o_qq      = o_q + (size_t)P_TOT*DDIM;            // 4096 f32
static const size_t o_KF      = o_qq + P_TOT;                        // 4096x512 f32
static const size_t o_keynorm = o_KF + (size_t)P_TOT*512;            // 4096
static const size_t o_centnorm= o_keynorm + MKEYS;                   // 256
static const size_t o_coef    = o_centnorm + CCENT;                  // 64
static const size_t o_vread   = o_coef + 64;                         // 4096x72 f32
static const size_t o_keysT   = o_vread + (size_t)P_TOT*72;          // 24x4096 f32
static const size_t o_sel     = o_keysT + (size_t)DDIM*MKEYS;        // 256 int
static const size_t o_mask    = o_sel + 256;                         // 4096 int
static const size_t o_count   = o_mask + MKEYS;                      // 64 int
static const size_t o_A6      = o_count + 64;                        // 4096x3072 bf16 [x0|x1|x2]
static const size_t o_W6T     = o_A6 + (size_t)P_TOT*3072/2;         // 72x6144 bf16
static const size_t o_W2cat   = o_W6T + (size_t)72*6144/2;           // 256x2048 bf16 [wh|wh]
static const size_t o_KCbf    = o_W2cat + (size_t)256*2048/2;        // 4096x512 bf16
static const size_t o_TTT     = o_KCbf + (size_t)P_TOT*512/2;        // 512x512 bf16
static const size_t o_Xcatbf  = o_TTT + (size_t)512*512/2;           // 4096x512 bf16
static const size_t o_W2T     = o_Xcatbf + (size_t)P_TOT*512/2;      // 72x512 bf16
static const size_t o_membf   = o_W2T + (size_t)72*512/2;            // 4096x96 bf16
static const size_t o_WoutT   = o_membf + (size_t)P_TOT*96/2;        // 1024x96 bf16

__device__ __forceinline__ float gelu_f(float x){
    return 0.5f * x * (1.0f + erff(x * 0.70710678118654752f));
}
__device__ __forceinline__ ushort f2bf(float f){
    union { float f; unsigned u; } a; a.f = f;
    unsigned u = a.u;
    return (ushort)((u + 0x7fffu + ((u >> 16) & 1u)) >> 16);
}
__device__ __forceinline__ float bf2f(ushort b){
    union { unsigned u; float f; } a; a.u = ((unsigned)b) << 16;
    return a.f;
}
__device__ __forceinline__ unsigned d2u(float f){
    unsigned b = __float_as_uint(f);
    return (b & 0x80000000u) ? ~b : (b | 0x80000000u);
}

#define TWO_PI_F 6.2831853071795864769f
#define STEP_F   0.024543692606170262f   // 2*pi/256

// ---------------- setup kernels ----------------
__global__ void setup_small(const float* __restrict__ fw, const float* __restrict__ cent,
                            float* __restrict__ coefp, float* __restrict__ centnorm,
                            int* __restrict__ sel, int* __restrict__ count)
{
    int t = threadIdx.x;
    if (t == 0){
        float m = fmaxf(fmaxf(fw[0],fw[1]),fmaxf(fw[2],fw[3]));
        float e0=expf(fw[0]-m), e1=expf(fw[1]-m), e2=expf(fw[2]-m), e3=expf(fw[3]-m);
        float s = e0+e1+e2+e3;
        *coefp = (e0 + e1*0.25f + e2*0.0625f + e3*0.015625f) / s;
        *count = 0;
    }
    if (t < CCENT){
        sel[t] = 0;
        float s = 0.f;
        #pragma unroll
        for (int d=0; d<DDIM; ++d){ float v = cent[t*DDIM+d]; s += v*v; }
        centnorm[t] = s;
    }
}

__global__ void key_setup(const float* __restrict__ keys, float* __restrict__ keynorm,
                          float* __restrict__ keysT)
{
    int m = blockIdx.x*256 + threadIdx.x;
    float s = 0.f;
    #pragma unroll
    for (int d=0; d<DDIM; ++d){
        float v = keys[m*DDIM+d]; s += v*v;
        keysT[(size_t)d*MKEYS + m] = v;
    }
    keynorm[m] = s;
}

// x -> triple-split bf16: A6[p] = [x0(1024) | x1(1024) | x2(1024)]
__global__ void conv_x3(const float* __restrict__ x, ushort* __restrict__ A6)
{
    int i = blockIdx.x*256 + threadIdx.x;
    int p = i >> 8, j = (i & 255) * 4;
    float4 v = *(const float4*)&x[(size_t)p*IN_DIM + j];
    ushort4 s0, s1, s2;
    float r;
    s0.x=f2bf(v.x); r=v.x-bf2f(s0.x); s1.x=f2bf(r); s2.x=f2bf(r-bf2f(s1.x));
    s0.y=f2bf(v.y); r=v.y-bf2f(s0.y); s1.y=f2bf(r); s2.y=f2bf(r-bf2f(s1.y));
    s0.z=f2bf(v.z); r=v.z-bf2f(s0.z); s1.z=f2bf(r); s2.z=f2bf(r-bf2f(s1.z));
    s0.w=f2bf(v.w); r=v.w-bf2f(s0.w); s1.w=f2bf(r); s2.w=f2bf(r-bf2f(s1.w));
    *(ushort4*)&A6[(size_t)p*3072 + j]        = s0;
    *(ushort4*)&A6[(size_t)p*3072 + 1024 + j] = s1;
    *(ushort4*)&A6[(size_t)p*3072 + 2048 + j] = s2;
}

// W6T[n][seg*1024+k] : B-side segment pattern [w0,w1,w0,w2,w1,w0]
__global__ void conv_W6(const float* __restrict__ Win, ushort* __restrict__ W6T)
{
    int idx = blockIdx.x*256 + threadIdx.x;    // 72*6144
    if (idx >= 72*6144) return;
    int n = idx / 6144, kp = idx - n*6144;
    int seg = kp >> 10, kk = kp & 1023;
    int sb = (0x012010 >> (seg << 2)) & 0xF;
    float w = Win[kk*72 + n];
    ushort w0 = f2bf(w);
    float r1 = w - bf2f(w0);
    ushort w1 = f2bf(r1);
    ushort w2 = f2bf(r1 - bf2f(w1));
    W6T[idx] = (sb == 0) ? w0 : (sb == 1 ? w1 : w2);
}

// W2cat[n] = [wh(1024) | wh(1024)], n = phase col (Wk col)
__global__ void conv_W2cat(const float* __restrict__ Wk, ushort* __restrict__ W2cat)
{
    int idx = blockIdx.x*256 + threadIdx.x;    // 256*2048
    int n = idx >> 11, k = idx & 2047;
    int kk = k & 1023;
    W2cat[idx] = f2bf(Wk[kk*256 + n]);
}

__global__ void conv_WoutT(const float* __restrict__ Wout, ushort* __restrict__ WoutT)
{
    int idx = blockIdx.x*256 + threadIdx.x;    // 1024*96
    int n = idx / 96, k = idx - n*96;
    float v = (k < 72) ? Wout[(size_t)k*IN_DIM + n] : 0.f;
    WoutT[idx] = f2bf(v);
}

// forward-DFT + entangle folded, transposed bf16: TTT[c][r]
__global__ void build_TTT(const float* __restrict__ ek, ushort* __restrict__ TTT)
{
    int idx = blockIdx.x*256 + threadIdx.x;   // 512*512, idx = c*512 + r
    int c = idx >> 9, r = idx & 511;
    int n = c & 255, h = r & 255;
    float th = (float)((n*h) & 255) * STEP_F - ek[n];
    float sn, cs; sincosf(th, &sn, &cs);
    float v;
    if (r < 256) v = (c < 256) ? cs : -sn;
    else         v = (c < 256) ? sn : cs;
    TTT[idx] = f2bf(v);
}

// inverse-DFT folded into W_read, transposed bf16: W2T[j][k]
__global__ void build_W2T(const float* __restrict__ Wr, ushort* __restrict__ W2T)
{
    __shared__ float tab[256];
    int t = threadIdx.x;
    tab[t] = cosf((float)t * STEP_F);
    __syncthreads();
    int idx = blockIdx.x*256 + t;   // 72*512
    if (idx >= 72*512) return;
    int j = idx >> 9, k = idx & 511;
    int n = k & 255;
    float acc = 0.f;
    for (int h=0; h<256; ++h){
        int xdx = (n*h) & 255;
        float c = tab[xdx], s = tab[(xdx+192) & 255];
        float w1 = Wr[h*72 + j], w2 = Wr[(256+h)*72 + j];
        acc += (k < 256) ? (c*w1 + s*w2) : (c*w2 - s*w1);
    }
    W2T[idx] = f2bf(acc * (1.f/256.f));
}

// ---------------- bf16 MFMA GEMM (with optional split-K over blockIdx.z) ----------------
__global__ __launch_bounds__(256) void gemm_bf16(
    const ushort* __restrict__ A, const ushort* __restrict__ BT,
    float* __restrict__ C, const float* __restrict__ bias,
    const float* __restrict__ addm, ushort* __restrict__ Cbf,
    int M, int N, int Kloop, int Nb, int NbfPad, int lda, int ldb, int aMask,
    int amode, int kChunk, size_t zStride)
{
    __shared__ __align__(16) ushort As[64][40];
    __shared__ __align__(16) ushort Bs[64][40];
    const int tid = threadIdx.x;
    const int lane = tid & 63, wid = tid >> 6;
    const int wm = wid >> 1, wn = wid & 1;
    const int m0 = blockIdx.y * 64, n0 = blockIdx.x * 64;
    const int fr = lane & 15, fc = lane >> 4;
    const int srow = tid >> 2, schunk = (tid & 3) * 8;
    const int kStart = blockIdx.z * kChunk;
    const int kEnd = (kStart + kChunk < Kloop) ? (kStart + kChunk) : Kloop;
    if (blockIdx.z){ C += zStride; bias = nullptr; addm = nullptr; Cbf = nullptr; }
    f32x4 acc[2][2] = {};
    for (int k0 = kStart; k0 < kEnd; k0 += 32){
        int kk = k0 + schunk;
        int ka;
        if (amode) ka = (((0x210100 >> ((kk >> 10) << 2)) & 0xF) << 10) | (kk & 1023);
        else       ka = kk & aMask;
        *(bf16x8*)&As[srow][schunk] =
            *(const bf16x8*)&A[(size_t)(m0 + srow) * lda + ka];
        {
            int n = n0 + srow;
            bf16x8 v = {};
            if (n < Nb) v = *(const bf16x8*)&BT[(size_t)n * ldb + kk];
            *(bf16x8*)&Bs[srow][schunk] = v;
        }
        __syncthreads();
        bf16x8 a0 = *(bf16x8*)&As[wm*32 + fr][fc*8];
        bf16x8 a1 = *(bf16x8*)&As[wm*32 + 16 + fr][fc*8];
        bf16x8 b0 = *(bf16x8*)&Bs[wn*32 + fr][fc*8];
        bf16x8 b1 = *(bf16x8*)&Bs[wn*32 + 16 + fr][fc*8];
        acc[0][0] = __builtin_amdgcn_mfma_f32_16x16x32_bf16(a0, b0, acc[0][0], 0,0,0);
        acc[0][1] = __builtin_amdgcn_mfma_f32_16x16x32_bf16(a0, b1, acc[0][1], 0,0,0);
        acc[1][0] = __builtin_amdgcn_mfma_f32_16x16x32_bf16(a1, b0, acc[1][0], 0,0,0);
        acc[1][1] = __builtin_amdgcn_mfma_f32_16x16x32_bf16(a1, b1, acc[1][1], 0,0,0);
        __syncthreads();
    }
    #pragma unroll
    for (int mi=0; mi<2; ++mi){
        #pragma unroll
        for (int ni=0; ni<2; ++ni){
            #pragma unroll
            for (int rr=0; rr<4; ++rr){
                int gm = m0 + wm*32 + mi*16 + fc*4 + rr;
                int gn = n0 + wn*32 + ni*16 + fr;
                float v = acc[mi][ni][rr];
                if (gn < N){
                    if (bias) v += bias[gn];
                    if (addm) v += addm[(size_t)gm*N + gn];
                    if (C) C[(size_t)gm*N + gn] = v;
                } else v = 0.f;
                if (Cbf && gn < NbfPad)
                    Cbf[(size_t)gm*NbfPad + gn] = f2bf(v);
            }
        }
    }
}

// ---------------- LN+GELU+ricci (Yq = half0 + half1) + phase (from Yp) ----------------
__global__ __launch_bounds__(256) void post_proj(
    const float* __restrict__ Yq, const float* __restrict__ Yp,
    const float* __restrict__ ricci,
    float* __restrict__ q, float* __restrict__ qq, ushort* __restrict__ KCbf)
{
    int wave = threadIdx.x >> 6, lane = threadIdx.x & 63;
    int p = blockIdx.x*4 + wave;
    __shared__ float zsh[4][72];
    __shared__ float zbsh[4][24];
    const float* Yr  = Yq + (size_t)p*72;
    const float* Yr2 = Yq + (size_t)P_TOT*72 + (size_t)p*72;
    float v1 = Yr[lane] + Yr2[lane];
    float v2 = (lane < 8) ? (Yr[64+lane] + Yr2[64+lane]) : 0.f;
    float s = v1 + v2, s2 = v1*v1 + v2*v2;
    #pragma unroll
    for (int off=32; off; off>>=1){ s += __shfl_xor(s,off); s2 += __shfl_xor(s2,off); }
    float mean = s * (1.f/72.f);
    float var  = s2 * (1.f/72.f) - mean*mean;
    float rstd = rsqrtf(var + 1e-5f);
    zsh[wave][lane] = gelu_f((v1-mean)*rstd);
    if (lane < 8) zsh[wave][64+lane] = gelu_f((v2-mean)*rstd);
    __syncthreads();
    if (lane < 24){
        float zb = (zsh[wave][lane*3] + zsh[wave][lane*3+1] + zsh[wave][lane*3+2]) * (1.f/3.f);
        zbsh[wave][lane] = zb;
    }
    __syncthreads();
    float qd = 0.f;
    if (lane < 24){
        #pragma unroll
        for (int e=0;e<24;++e) qd += zbsh[wave][e] * ricci[e*24+lane];
        q[(size_t)p*DDIM + lane] = qd;
    }
    float qs = (lane<24) ? qd*qd : 0.f;
    #pragma unroll
    for (int off=32; off; off>>=1) qs += __shfl_xor(qs,off);
    if (lane == 0) qq[p] = qs;
    const float* Ypr = Yp + (size_t)p*256;
    #pragma unroll
    for (int j=0;j<4;++j){
        int h = lane + 64*j;
        float u = Ypr[h];
        float ph = TWO_PI_F / (1.f + expf(-u));
        float sn, cs; sincosf(ph, &sn, &cs);
        KCbf[(size_t)p*512 + h]       = f2bf(cs);
        KCbf[(size_t)p*512 + 256 + h] = f2bf(sn);
    }
}

// ---------------- centroid top-8 (fp32), global union ----------------
__global__ __launch_bounds__(256) void cent_topk(
    const float* __restrict__ q, const float* __restrict__ qq,
    const float* __restrict__ centroids, const float* __restrict__ centnorm,
    int* __restrict__ sel)
{
    int wave = threadIdx.x >> 6, lane = threadIdx.x & 63;
    int p = blockIdx.x*4 + wave;
    __shared__ float qsh[4][24];
    if (lane < 24) qsh[wave][lane] = q[(size_t)p*DDIM + lane];
    __syncthreads();
    float qv = qq[p];
    float d[4]; int ci[4];
    #pragma unroll
    for (int j=0;j<4;++j){
        int c = lane + 64*j;
        float dot = 0.f;
        #pragma unroll
        for (int e=0;e<24;++e) dot += qsh[wave][e]*centroids[c*24+e];
        d[j] = qv + centnorm[c] - 2.f*dot;
        ci[j] = c;
    }
    for (int k=0;k<8;++k){
        float mv = d[0]; int mi = ci[0];
        #pragma unroll
        for (int j=1;j<4;++j) if (d[j] < mv || (d[j]==mv && ci[j]<mi)){ mv=d[j]; mi=ci[j]; }
        #pragma unroll
        for (int off=32; off; off>>=1){
            float ov = __shfl_xor(mv,off); int oi = __shfl_xor(mi,off);
            if (ov < mv || (ov==mv && oi<mi)){ mv=ov; mi=oi; }
        }
        if ((mi & 63) == lane){
            int j = mi >> 6;
            if (j==0) d[0]=INFINITY; else if (j==1) d[1]=INFINITY;
            else if (j==2) d[2]=INFINITY; else d[3]=INFINITY;
            sel[mi] = 1;
        }
    }
}

__global__ void mask_count(const int* __restrict__ sel, const int* __restrict__ cids,
                           int* __restrict__ maskKey, int* __restrict__ count)
{
    int m = blockIdx.x*256 + threadIdx.x;
    int v = sel[cids[m]];
    maskKey[m] = v;
    int lane = threadIdx.x & 63;
    #pragma unroll
    for (int off=32; off; off>>=1) v += __shfl_xor(v, off);
    if (lane == 0) atomicAdd(count, v);
}

// ---------------- radix-select top-32 helper (exact, tie-break = smallest idx) ----------------
__device__ __forceinline__ void select_pos(
    int pc, float (&dvr)[16], int t, int lane, int w, float coef,
    int* hist, int* wsum,
    unsigned& s_pref, int& s_krem, int& s_bin, int& s_below,
    int& s_cntL, int& s_cntT,
    float* candD, int* candI, float* tieD, int* tieI,
    float (*sw4)[KTOP], int (*sidx4)[KTOP], float* inv4)
{
    if (t == 0){ s_pref = 0u; s_krem = KTOP; }
    __syncthreads();
    for (int pp = 0; pp < 4; ++pp){
        hist[t] = 0;
        __syncthreads();
        unsigned prefR = s_pref;
        int kremR = s_krem;
        #pragma unroll
        for (int i=0;i<16;++i){
            unsigned u = d2u(dvr[i]);
            bool cond = (pp == 0) ? true : ((u >> (32 - 8*pp)) == prefR);
            if (cond) atomicAdd(&hist[(u >> (24 - 8*pp)) & 255], 1);
        }
        __syncthreads();
        int h = hist[t];
        int sc = h;
        #pragma unroll
        for (int off=1; off<64; off<<=1){
            int o = __shfl_up(sc, off);
            if (lane >= off) sc += o;
        }
        if (lane == 63) wsum[w] = sc;
        __syncthreads();
        int add = 0;
        for (int ww=0; ww<w; ++ww) add += wsum[ww];
        sc += add;
        if (kremR > sc - h && kremR <= sc){ s_bin = t; s_below = sc - h; }
        __syncthreads();
        if (t == 0){ s_pref = (s_pref << 8) | (unsigned)s_bin; s_krem -= s_below; }
        __syncthreads();
    }
    unsigned tau = s_pref;
    if (t == 0){ s_cntL = 0; s_cntT = 0; }
    __syncthreads();
    #pragma unroll
    for (int i=0;i<16;++i){
        unsigned u = d2u(dvr[i]);
        int m = 1024*(i>>2) + 4*t + (i&3);
        if (u < tau){ int sl = atomicAdd(&s_cntL,1); candD[sl]=dvr[i]; candI[sl]=m; }
        else if (u == tau){ int sl = atomicAdd(&s_cntT,1); if (sl<64){ tieD[sl]=dvr[i]; tieI[sl]=m; } }
    }
    __syncthreads();
    if (t == 0){
        int need = s_krem, have = s_cntL;
        int nt = s_cntT < 64 ? s_cntT : 64;
        for (int sl=0; sl<need; ++sl){
            int best=0, bi=0x7fffffff;
            for (int j=0;j<nt;++j) if (tieI[j] < bi){ bi=tieI[j]; best=j; }
            candD[have+sl]=tieD[best]; candI[have+sl]=bi; tieI[best]=0x7fffffff;
        }
    }
    __syncthreads();
    if (w == 0){
        float v = (lane < 32) ? candD[lane] : INFINITY;
        int  ix = (lane < 32) ? candI[lane] : 0x7fffffff;
        #pragma unroll
        for (int kk=2; kk<=64; kk<<=1){
            #pragma unroll
            for (int j=kk>>1; j>0; j>>=1){
                float ov = __shfl_xor(v, j); int oi = __shfl_xor(ix, j);
                bool keepSmall = (((lane & j) == 0) == ((lane & kk) == 0));
                bool less = (ov < v) || (ov == v && oi < ix);
                if (keepSmall ? less : !less){ v = ov; ix = oi; }
            }
        }
        float v0 = __shfl(v, 0);
        float swv = (lane < 32) ? expf(-coef * (v - v0)) : 0.f;
        float ssum = 0.f;
        for (int k=0;k<KTOP;++k) ssum += __shfl(swv, k);
        if (lane < 32){ sw4[pc][lane] = swv; sidx4[pc][lane] = ix; }
        if (lane == 0) inv4[pc] = 1.f / ssum;
    }
    __syncthreads();
}

// ---------------- top-32 select (radix, 4 positions/block) + value/holo read ----------------
__global__ __launch_bounds__(256) void select_read(
    const float* __restrict__ keysT,
    const float* __restrict__ q, const float* __restrict__ qq,
    const float* __restrict__ keynorm, const int* __restrict__ maskKey,
    const int* __restrict__ count, const float* __restrict__ coefp,
    const float* __restrict__ values, const float* __restrict__ hr,
    const float* __restrict__ hi, const float* __restrict__ KF,
    float* __restrict__ vread, ushort* __restrict__ Xcatbf)
{
    const int t = threadIdx.x;
    const int w = t >> 6, lane = t & 63;
    const int p0 = blockIdx.x * 4;
    __shared__ float qsh[4][24];
    __shared__ int hist[256];
    __shared__ int wsum[4];
    __shared__ unsigned s_pref;
    __shared__ int s_krem, s_bin, s_below, s_cntL, s_cntT;
    __shared__ float candD[KTOP]; __shared__ int candI[KTOP];
    __shared__ float tieD[64];    __shared__ int tieI[64];
    __shared__ float sw4[4][KTOP]; __shared__ int sidx4[4][KTOP];
    __shared__ float inv4[4];

    bool useAll = (*count) < 32;
    float coef = *coefp;
    if (t < 96){
        int pp = t / 24, e = t - pp*24;
        qsh[pp][e] = q[(size_t)(p0+pp)*DDIM + e];
    }
    __syncthreads();
    float qv0 = qq[p0], qv1 = qq[p0+1], qv2 = qq[p0+2], qv3 = qq[p0+3];

    // distances: thread t owns keys m = 1024*i + 4*t + j (i<4, j<4), float4 loads
    float a0[16], a1[16], a2[16], a3[16];
    #pragma unroll
    for (int i=0;i<16;++i){ a0[i]=0.f; a1[i]=0.f; a2[i]=0.f; a3[i]=0.f; }
    for (int e=0;e<24;++e){
        float q0 = qsh[0][e], q1 = qsh[1][e], q2 = qsh[2][e], q3 = qsh[3][e];
        const float* kr = keysT + (size_t)e*MKEYS + 4*t;
        #pragma unroll
        for (int i=0;i<4;++i){
            float4 kv = *(const float4*)&kr[1024*i];
            a0[i*4+0]=fmaf(q0,kv.x,a0[i*4+0]); a0[i*4+1]=fmaf(q0,kv.y,a0[i*4+1]);
            a0[i*4+2]=fmaf(q0,kv.z,a0[i*4+2]); a0[i*4+3]=fmaf(q0,kv.w,a0[i*4+3]);
            a1[i*4+0]=fmaf(q1,kv.x,a1[i*4+0]); a1[i*4+1]=fmaf(q1,kv.y,a1[i*4+1]);
            a1[i*4+2]=fmaf(q1,kv.z,a1[i*4+2]); a1[i*4+3]=fmaf(q1,kv.w,a1[i*4+3]);
            a2[i*4+0]=fmaf(q2,kv.x,a2[i*4+0]); a2[i*4+1]=fmaf(q2,kv.y,a2[i*4+1]);
            a2[i*4+2]=fmaf(q2,kv.z,a2[i*4+2]); a2[i*4+3]=fmaf(q2,kv.w,a2[i*4+3]);
            a3[i*4+0]=fmaf(q3,kv.x,a3[i*4+0]); a3[i*4+1]=fmaf(q3,kv.y,a3[i*4+1]);
            a3[i*4+2]=fmaf(q3,kv.z,a3[i*4+2]); a3[i*4+3]=fmaf(q3,kv.w,a3[i*4+3]);
        }
    }
    // transform to distances with mask
    #pragma unroll
    for (int i=0;i<4;++i){
        float4 kn = *(const float4*)&keynorm[1024*i + 4*t];
        int4 mk = *(const int4*)&maskKey[1024*i + 4*t];
        bool ok0 = useAll || mk.x, ok1 = useAll || mk.y, ok2 = useAll || mk.z, ok3 = useAll || mk.w;
        float d;
        d = qv0 + kn.x - 2.f*a0[i*4+0]; a0[i*4+0] = ok0 ? d : INFINITY;
        d = qv0 + kn.y - 2.f*a0[i*4+1]; a0[i*4+1] = ok1 ? d : INFINITY;
        d = qv0 + kn.z - 2.f*a0[i*4+2]; a0[i*4+2] = ok2 ? d : INFINITY;
        d = qv0 + kn.w - 2.f*a0[i*4+3]; a0[i*4+3] = ok3 ? d : INFINITY;
        d = qv1 + kn.x - 2.f*a1[i*4+0]; a1[i*4+0] = ok0 ? d : INFINITY;
        d = qv1 + kn.y - 2.f*a1[i*4+1]; a1[i*4+1] = ok1 ? d : INFINITY;
        d = qv1 + kn.z - 2.f*a1[i*4+2]; a1[i*4+2] = ok2 ? d : INFINITY;
        d = qv1 + kn.w - 2.f*a1[i*4+3]; a1[i*4+3] = ok3 ? d : INFINITY;
        d = qv2 + kn.x - 2.f*a2[i*4+0]; a2[i*4+0] = ok0 ? d : INFINITY;
        d = qv2 + kn.y - 2.f*a2[i*4+1]; a2[i*4+1] = ok1 ? d : INFINITY;
        d = qv2 + kn.z - 2.f*a2[i*4+2]; a2[i*4+2] = ok2 ? d : INFINITY;
        d = qv2 + kn.w - 2.f*a2[i*4+3]; a2[i*4+3] = ok3 ? d : INFINITY;
        d = qv3 + kn.x - 2.f*a3[i*4+0]; a3[i*4+0] = ok0 ? d : INFINITY;
        d = qv3 + kn.y - 2.f*a3[i*4+1]; a3[i*4+1] = ok1 ? d : INFINITY;
        d = qv3 + kn.z - 2.f*a3[i*4+2]; a3[i*4+2] = ok2 ? d : INFINITY;
        d = qv3 + kn.w - 2.f*a3[i*4+3]; a3[i*4+3] = ok3 ? d : INFINITY;
    }

    select_pos(0, a0, t, lane, w, coef, hist, wsum, s_pref, s_krem, s_bin, s_below,
               s_cntL, s_cntT, candD, candI, tieD, tieI, sw4, sidx4, inv4);
    select_pos(1, a1, t, lane, w, coef, hist, wsum, s_pref, s_krem, s_bin, s_below,
               s_cntL, s_cntT, candD, candI, tieD, tieI, sw4, sidx4, inv4);
    select_pos(2, a2, t, lane, w, coef, hist, wsum, s_pref, s_krem, s_bin, s_below,
               s_cntL, s_cntT, candD, candI, tieD, tieI, sw4, sidx4, inv4);
    select_pos(3, a3, t, lane, w, coef, hist, wsum, s_pref, s_krem, s_bin, s_below,
               s_cntL, s_cntT, candD, candI, tieD, tieI, sw4, sidx4, inv4);

    // gather + write, positions sequential (LDS-indexed, registers free)
    for (int pos=0; pos<4; ++pos){
        int p = p0 + pos;
        float inv = inv4[pos];
        if (t < 72){
            float a = 0.f;
            for (int k=0;k<KTOP;++k) a += sw4[pos][k]*values[(size_t)sidx4[pos][k]*72 + t];
            vread[(size_t)p*72 + t] = a * inv;
        }
        float sr = 0.f, si = 0.f;
        for (int k=0;k<KTOP;++k){
            float wv = sw4[pos][k];
            size_t off = (size_t)sidx4[pos][k]*HDIM + t;
            sr += wv*hr[off]; si += wv*hi[off];
        }
        sr *= inv; si *= inv;
        float Rk = KF[(size_t)p*512 + t], Ik = KF[(size_t)p*512 + 256 + t];
        Xcatbf[(size_t)p*512 + t]       = f2bf(sr*Rk + si*Ik);
        Xcatbf[(size_t)p*512 + 256 + t] = f2bf(si*Rk - sr*Ik);
    }
}

// ---------------- final LN+GELU, in place on d_out ----------------
__global__ __launch_bounds__(256) void ln_gelu_out(float* __restrict__ O)
{
    int p = blockIdx.x; int t = threadIdx.x;
    float4 v = *(float4*)&O[(size_t)p*IN_DIM + t*4];
    float s  = v.x+v.y+v.z+v.w;
    float s2 = v.x*v.x+v.y*v.y+v.z*v.z+v.w*v.w;
    #pragma unroll
    for (int off=32; off; off>>=1){ s += __shfl_xor(s,off); s2 += __shfl_xor(s2,off); }
    __shared__ float as[4], as2[4];
    int lane = t & 63, w = t >> 6;
    if (lane == 0){ as[w] = s; as2[w] = s2; }
    __syncthreads();
    s = as[0]+as[1]+as[2]+as[3];
    s2 = as2[0]+as2[1]+as2[2]+as2[3];
    float mean = s * (1.f/1024.f);
    float var  = s2 * (1.f/1024.f) - mean*mean;
    float rstd = rsqrtf(var + 1e-5f);
    v.x = gelu_f((v.x-mean)*rstd);
    v.y = gelu_f((v.y-mean)*rstd);
    v.z = gelu_f((v.z-mean)*rstd);
    v.w = gelu_f((v.w-mean)*rstd);
    *(float4*)&O[(size_t)p*IN_DIM + t*4] = v;
}

extern "C" void kernel_launch(void* const* d_in, const int* in_sizes, int n_in,
                              void* d_out, int out_size, void* d_ws, size_t ws_size,
                              hipStream_t stream)
{
    const float* x      = (const float*)d_in[0];
    const float* keys   = (const float*)d_in[1];
    const float* values = (const float*)d_in[2];
    const float* W_in   = (const float*)d_in[3];
    const float* b_in   = (const float*)d_in[4];
    const float* ricci  = (const float*)d_in[5];
    const float* fw     = (const float*)d_in[6];
    const float* cent   = (const float*)d_in[7];
    const float* Wk     = (const float*)d_in[8];
    const float* bk     = (const float*)d_in[9];
    const float* ek     = (const float*)d_in[10];
    const float* hr     = (const float*)d_in[11];
    const float* hi     = (const float*)d_in[12];
    const float* Wr     = (const float*)d_in[13];
    const float* brd    = (const float*)d_in[14];
    const float* W_out  = (const float*)d_in[15];
    const float* b_out  = (const float*)d_in[16];
    const int*   cids   = (const int*)d_in[17];
    float* ws  = (float*)d_ws;
    float* out = (float*)d_out;
    int* sel   = (int*)(ws + o_sel);
    int* mask  = (int*)(ws + o_mask);
    int* count = (int*)(ws + o_count);
    ushort* A6     = (ushort*)(ws + o_A6);
    ushort* W6T    = (ushort*)(ws + o_W6T);
    ushort* W2cat  = (ushort*)(ws + o_W2cat);
    ushort* KCbf   = (ushort*)(ws + o_KCbf);
    ushort* TTT    = (ushort*)(ws + o_TTT);
    ushort* Xcatbf = (ushort*)(ws + o_Xcatbf);
    ushort* W2T    = (ushort*)(ws + o_W2T);
    ushort* membf  = (ushort*)(ws + o_membf);
    ushort* WoutT  = (ushort*)(ws + o_WoutT);
    const int NOMASK = 0x7fffffff;

    setup_small<<<1,256,0,stream>>>(fw, cent, ws+o_coef, ws+o_centnorm, sel, count);
    key_setup<<<16,256,0,stream>>>(keys, ws+o_keynorm, ws+o_keysT);
    conv_x3<<<4096,256,0,stream>>>(x, A6);
    conv_W6<<<(72*6144+255)/256,256,0,stream>>>(W_in, W6T);
    conv_W2cat<<<2048,256,0,stream>>>(Wk, W2cat);
    conv_WoutT<<<(IN_DIM*96)/256,256,0,stream>>>(W_out, WoutT);
    build_TTT<<<1024,256,0,stream>>>(ek, TTT);
    build_W2T<<<144,256,0,stream>>>(Wr, W2T);

    // Yq = x @ W_in + b_in : 6-term bf16 split MFMA, split-K z=2 (segs 0-2 | 3-5)
    gemm_bf16<<<dim3(2,64,2),256,0,stream>>>(A6, W6T, ws+o_Yq, b_in, nullptr, nullptr,
                                             P_TOT, 72, 6144, 72, 0, 3072, 6144, NOMASK, 1,
                                             3072, (size_t)P_TOT*72);
    // Yp = x @ Wk + bk (smooth phase path): [x0|x1] @ [wh|wh]
    gemm_bf16<<<dim3(4,64,1),256,0,stream>>>(A6, W2cat, ws+o_Yp, bk, nullptr, nullptr,
                                             P_TOT, 256, 2048, 256, 0, 3072, 2048, NOMASK, 0,
                                             2048, 0);
    post_proj<<<1024,256,0,stream>>>(ws+o_Yq, ws+o_Yp, ricci, ws+o_q, ws+o_qq, KCbf);
    // KF = KC @ TT  (forward FFT + entangle, smooth)
    gemm_bf16<<<dim3(8,64,1),256,0,stream>>>(KCbf, TTT, ws+o_KF, nullptr, nullptr, nullptr,
                                             P_TOT, 512, 512, 512, 0, 512, 512, NOMASK, 0,
                                             512, 0);
    cent_topk<<<1024,256,0,stream>>>(ws+o_q, ws+o_qq, cent, ws+o_centnorm, sel);
    mask_count<<<16,256,0,stream>>>(sel, cids, mask, count);
    select_read<<<P_TOT/4,256,0,stream>>>(ws+o_keysT, ws+o_q, ws+o_qq, ws+o_keynorm,
                                          mask, count, ws+o_coef, values, hr, hi, ws+o_KF,
                                          ws+o_vread, Xcatbf);
    // mem = Xcat @ W2 + b_read + vread  -> bf16 (padded to 96 cols)
    gemm_bf16<<<dim3(2,64,1),256,0,stream>>>(Xcatbf, W2T, nullptr, brd, ws+o_vread, membf,
                                             P_TOT, 72, 512, 72, 96, 512, 512, NOMASK, 0,
                                             512, 0);
    // out = mem @ W_out + b_out
    gemm_bf16<<<dim3(16,64,1),256,0,stream>>>(membf, WoutT, out, b_out, nullptr, nullptr,
                                              P_TOT, IN_DIM, 96, IN_DIM, 0, 96, 96, NOMASK, 0,
                                              96, 0);
    ln_gelu_out<<<P_TOT,256,0,stream>>>(out);
}